// Round 1
// baseline (200.677 us; speedup 1.0000x reference)
//
#include <hip/hip_runtime.h>

// Problem constants (from reference)
#define C_IN    7
#define NKER    586
#define KH      8
#define SEQ     4096
#define T_LEN   (SEQ * 3)      // 12288 gathered positions
#define HP      (T_LEN + 1)    // 12289 output positions
#define NC      4096           // output channels (7*585 + 1)
#define KO_N    585            // kernels per g-channel for the main block

#define H_TILE  64
#define BLOCK   256
#define CPT     4              // channels per thread (float4 store)
#define C_PER_BLOCK (BLOCK * CPT)   // 1024
#define GROW    (H_TILE + 7)   // g values needed per channel per tile

__global__ __launch_bounds__(BLOCK) void conv1d_gather_kernel(
    const float* __restrict__ x,      // (SEQ, C_IN)
    const float* __restrict__ kern,   // (NKER, KH, 3)
    float* __restrict__ out)          // flat[h*NC + c]
{
    __shared__ float g[C_IN][GROW + 1];   // +1 pad

    const int h0  = blockIdx.y * H_TILE;
    const int c0  = blockIdx.x * C_PER_BLOCK;
    const int tid = threadIdx.x;

    // ---- Stage g[ci][tt] for t = h0-4 .. h0+H_TILE+2 (zero outside [0,T_LEN)) ----
    const int GCNT = C_IN * GROW;  // 497
    for (int i = tid; i < GCNT; i += BLOCK) {
        int ci = i / GROW;
        int tt = i - ci * GROW;
        int t  = h0 - 4 + tt;
        float v = 0.0f;
        if (t >= 0 && t < T_LEN) {
            int s  = t / 3;              // magic-mul
            int j  = t - 3 * s;
            int si = s + j;
            si = (si > SEQ - 1) ? (SEQ - 1) : si;
            v = x[si * C_IN + ci];
        }
        g[ci][tt] = v;
    }
    __syncthreads();

    const int cbase = c0 + tid * CPT;    // multiple of 4, never 4095

    // ---- Per-channel kernel index + g-channel selection ----
    float taps[CPT][KH];
    int   useB[CPT];
    const int ciA = cbase / KO_N;        // <= 6
    int ciB = ciA;
    #pragma unroll
    for (int j = 0; j < CPT; j++) {
        int c = cbase + j;
        int gci, kidx;
        if (c == NC - 1) { gci = 0; kidx = NKER - 1; }   // last row: g[0] * kernels[585]
        else             { gci = c / KO_N; kidx = c - KO_N * gci; }
        useB[j] = (gci != ciA);
        if (gci != ciA) ciB = gci;
        #pragma unroll
        for (int k = 0; k < KH; k++)
            taps[j][k] = kern[kidx * (KH * 3) + k * 3 + 1];   // middle column only
    }

    // ---- Sliding windows in registers ----
    float winA[KH], winB[KH];
    #pragma unroll
    for (int k = 0; k < KH; k++) { winA[k] = g[ciA][k]; winB[k] = g[ciB][k]; }

    int hend = HP - h0; if (hend > H_TILE) hend = H_TILE;
    float* outp = out + (size_t)h0 * NC + cbase;

    #pragma unroll 8
    for (int hh = 0; hh < hend; hh++) {
        float dA[CPT], dB[CPT];
        #pragma unroll
        for (int j = 0; j < CPT; j++) { dA[j] = 0.0f; dB[j] = 0.0f; }
        #pragma unroll
        for (int k = 0; k < KH; k++) {
            #pragma unroll
            for (int j = 0; j < CPT; j++) {
                dA[j] = fmaf(winA[k], taps[j][k], dA[j]);
                dB[j] = fmaf(winB[k], taps[j][k], dB[j]);
            }
        }
        float4 o;
        o.x = useB[0] ? dB[0] : dA[0];
        o.y = useB[1] ? dB[1] : dA[1];
        o.z = useB[2] ? dB[2] : dA[2];
        o.w = useB[3] ? dB[3] : dA[3];
        *reinterpret_cast<float4*>(outp) = o;
        outp += NC;

        // slide window by one position
        #pragma unroll
        for (int k = 0; k < KH - 1; k++) { winA[k] = winA[k + 1]; winB[k] = winB[k + 1]; }
        winA[KH - 1] = g[ciA][hh + KH];
        winB[KH - 1] = g[ciB][hh + KH];
    }
}

extern "C" void kernel_launch(void* const* d_in, const int* in_sizes, int n_in,
                              void* d_out, int out_size, void* d_ws, size_t ws_size,
                              hipStream_t stream) {
    const float* x    = (const float*)d_in[0];   // (1, 4096, 7, 1) f32
    const float* kern = (const float*)d_in[1];   // (586, 8, 3) f32
    float* out        = (float*)d_out;           // 12289*4096 f32

    dim3 grid(NC / C_PER_BLOCK, (HP + H_TILE - 1) / H_TILE);  // (4, 193)
    conv1d_gather_kernel<<<grid, BLOCK, 0, stream>>>(x, kern, out);
}